// Round 1
// baseline (394.516 us; speedup 1.0000x reference)
//
#include <hip/hip_runtime.h>
#include <math.h>

// Problem: ConditionalSigKerMMDDiscriminator
// x,y,z: (64, 33, 8) fp32.  Output: scalar fp32.
//
// Pipeline:
//   K      = sigkernel_gram(rbf(x,x))        (64x64)
//   L_gen  = sigkernel_gram(lin(y,y))
//   L_true = sigkernel_gram(lin(z,z))
//   L_mix  = sigkernel_gram(lin(y,z))
//   Kinv   = (K + I)^-1
//   out    = sum_ij (Kinv K Kinv)[i,j] * (Lg + Lt - 2 Lm)[j,i]

#define NPATH 64
#define SLEN 33
#define DIM 8
#define F 2                     // 2^dyadic_order
#define P ((SLEN - 1) * F)      // 64 (PDE grid size)

// ---------------------------------------------------------------------------
// Kernel A: one wave per (i,j) pair per gram. grid = (4096, 4), block = 64.
// gram 0: rbf(x,x), 1: lin(y,y), 2: lin(z,z), 3: lin(y,z)
// ---------------------------------------------------------------------------
__global__ __launch_bounds__(64)
void sigker_pde_kernel(const float* __restrict__ x,
                       const float* __restrict__ y,
                       const float* __restrict__ z,
                       float* __restrict__ ws) {
    __shared__ float Xi[SLEN * DIM];          // 264
    __shared__ float Xj[SLEN * DIM];          // 264
    __shared__ float Gs[SLEN * 34];           // 33x33 tile, stride 34

    const int pair = blockIdx.x;
    const int gi = pair >> 6;       // row path index
    const int gj = pair & 63;       // col path index
    const int g  = blockIdx.y;
    const int lane = threadIdx.x;   // 0..63

    const float* Ap;
    const float* Bp;
    bool rbf = false;
    switch (g) {
        case 0: Ap = x; Bp = x; rbf = true; break;
        case 1: Ap = y; Bp = y; break;
        case 2: Ap = z; Bp = z; break;
        default: Ap = y; Bp = z; break;
    }

    // Stage the two paths into LDS
    for (int k = lane; k < SLEN * DIM; k += 64) {
        Xi[k] = Ap[gi * (SLEN * DIM) + k];
        Xj[k] = Bp[gj * (SLEN * DIM) + k];
    }
    __syncthreads();

    // Build 33x33 static-kernel tile
    for (int idx = lane; idx < SLEN * SLEN; idx += 64) {
        int s = idx / SLEN;
        int t = idx - s * SLEN;
        float acc = 0.0f;
        if (rbf) {
            #pragma unroll
            for (int d = 0; d < DIM; ++d) {
                float df = Xi[s * DIM + d] - Xj[t * DIM + d];
                acc += df * df;
            }
            acc = __expf(-acc);   // sigma = 1
        } else {
            #pragma unroll
            for (int d = 0; d < DIM; ++d)
                acc += Xi[s * DIM + d] * Xj[t * DIM + d];
        }
        Gs[s * 34 + t] = acc;
    }
    __syncthreads();

    // Anti-diagonal wavefront PDE solve on the 64x64 dyadic grid.
    // Lane p owns row p; at diagonal step d it computes cell (p, q=d-p),
    // which is k[p+1][q+1] in the (P+1)x(P+1) grid with unit boundary.
    float v_cur = 1.0f;   // own value at step d-1 (cell (p, q-1))
    float v_old = 1.0f;   // own value at step d-2 (cell (p, q-2))
    const int s0 = lane >> 1;
    for (int d = 0; d < 2 * P - 1; ++d) {
        float up_c = __shfl_up(v_cur, 1);   // lane p-1's value @ d-1 = k[p][q+1]
        float up_o = __shfl_up(v_old, 1);   // lane p-1's value @ d-2 = k[p][q]
        int q = d - lane;
        bool active = (q >= 0) && (q < P);

        float up   = (lane == 0) ? 1.0f : up_c;
        float updg = (lane == 0 || q == 0) ? 1.0f : up_o;
        float left = (q == 0) ? 1.0f : v_cur;

        int t = q >> 1;
        int tc = t < 0 ? 0 : (t > 31 ? 31 : t);
        float g00 = Gs[s0 * 34 + tc];
        float g01 = Gs[s0 * 34 + tc + 1];
        float g10 = Gs[(s0 + 1) * 34 + tc];
        float g11 = Gs[(s0 + 1) * 34 + tc + 1];
        float inc = (g11 - g10 - g01 + g00) * 0.25f;  // /= f*f

        float i2 = inc * inc * (1.0f / 12.0f);
        float c1 = 1.0f + 0.5f * inc + i2;
        float c2 = 1.0f - i2;
        float newv = (left + up) * c1 - updg * c2;
        if (active) { v_old = v_cur; v_cur = newv; }
    }

    if (lane == 63)
        ws[g * (NPATH * NPATH) + gi * NPATH + gj] = v_cur;
}

// ---------------------------------------------------------------------------
// Kernel B: single block of 256 threads: inverse + traces.
// ---------------------------------------------------------------------------
__global__ __launch_bounds__(256)
void final_kernel(const float* __restrict__ ws, float* __restrict__ out) {
    __shared__ float K[64 * 64];      // 16 KB
    __shared__ float M[64 * 128];     // 32 KB  augmented [K+I | I] -> [I | Kinv]
    __shared__ float T1[64 * 64];     // 16 KB  K @ Kinv
    __shared__ float fac[64];
    __shared__ float red[256];

    const int tid = threadIdx.x;
    const float* Kg = ws;
    const float* Lg = ws + 4096;
    const float* Lt = ws + 8192;
    const float* Lm = ws + 12288;

    for (int idx = tid; idx < 4096; idx += 256) K[idx] = Kg[idx];
    __syncthreads();

    // Init augmented matrix
    for (int idx = tid; idx < 64 * 128; idx += 256) {
        int r = idx >> 7, c = idx & 127;
        float v;
        if (c < 64) v = K[r * 64 + c] + ((r == c) ? 1.0f : 0.0f);
        else        v = ((c - 64) == r) ? 1.0f : 0.0f;
        M[idx] = v;
    }
    __syncthreads();

    // Gauss-Jordan (no pivoting: K+I is SPD, diag >= 1+lambda)
    for (int p = 0; p < 64; ++p) {
        float pinv = 1.0f / M[p * 128 + p];
        __syncthreads();
        if (tid < 128) {
            M[p * 128 + tid] *= pinv;
        } else if (tid < 192) {
            int r = tid - 128;
            if (r != p) fac[r] = M[r * 128 + p];
        }
        __syncthreads();
        for (int idx = tid; idx < 64 * 128; idx += 256) {
            int r = idx >> 7, c = idx & 127;
            if (r != p) M[idx] -= fac[r] * M[p * 128 + c];
        }
        __syncthreads();
    }
    // Kinv[r][c] = M[r*128 + 64 + c]

    // T1 = K @ Kinv
    for (int idx = tid; idx < 4096; idx += 256) {
        int i = idx >> 6, j = idx & 63;
        float acc = 0.0f;
        for (int k = 0; k < 64; ++k)
            acc += K[i * 64 + k] * M[k * 128 + 64 + j];
        T1[idx] = acc;
    }
    __syncthreads();

    // C = Kinv @ T1, fused with trace vs Lcomb[j][i]
    float local = 0.0f;
    for (int idx = tid; idx < 4096; idx += 256) {
        int i = idx >> 6, j = idx & 63;
        float acc = 0.0f;
        for (int k = 0; k < 64; ++k)
            acc += M[i * 128 + 64 + k] * T1[k * 64 + j];
        float lji = Lg[j * 64 + i] + Lt[j * 64 + i] - 2.0f * Lm[j * 64 + i];
        local += acc * lji;
    }

    red[tid] = local;
    __syncthreads();
    for (int s = 128; s > 0; s >>= 1) {
        if (tid < s) red[tid] += red[tid + s];
        __syncthreads();
    }
    if (tid == 0) out[0] = red[0];
}

extern "C" void kernel_launch(void* const* d_in, const int* in_sizes, int n_in,
                              void* d_out, int out_size, void* d_ws, size_t ws_size,
                              hipStream_t stream) {
    const float* x = (const float*)d_in[0];
    const float* y = (const float*)d_in[1];
    const float* z = (const float*)d_in[2];
    float* out = (float*)d_out;
    float* ws = (float*)d_ws;   // 4 * 4096 floats = 64 KB used

    dim3 gridA(NPATH * NPATH, 4);
    sigker_pde_kernel<<<gridA, 64, 0, stream>>>(x, y, z, ws);
    final_kernel<<<1, 256, 0, stream>>>(ws, out);
}

// Round 2
// 183.150 us; speedup vs baseline: 2.1541x; 2.1541x over previous
//
#include <hip/hip_runtime.h>
#include <math.h>

// ConditionalSigKerMMDDiscriminator — x,y,z: (64,33,8) fp32 -> scalar fp32.
//
//   K      = sigker(rbf(x,x))   [symmetric]
//   L_gen  = sigker(lin(y,y))   [symmetric]
//   L_true = sigker(lin(z,z))   [symmetric]
//   L_mix  = sigker(lin(y,z))   [full]
//   out    = tr(Kinv K Kinv L),  Kinv=(K+I)^-1,  L = Lg + Lt - 2 Lm
//
// ws layout (floats): [0]=K [4096]=Lg [8192]=Lt [12288]=Lm [16384]=Kinv [20480]=partial(64)

#define SLEN 33
#define PGRID 64   // (SLEN-1)*2^dyadic_order

// ---------------------------------------------------------------------------
// Kernel A: one wave per (i,j) pair per gram. grid=(4096,4), block=64.
// Anti-diagonal wavefront PDE; lane p owns grid row p.
// LDS ops per step: 1 shfl + 1 inc read (diag neighbor carried in register).
// ---------------------------------------------------------------------------
__global__ __launch_bounds__(64)
void sigker_pde_kernel(const float* __restrict__ x,
                       const float* __restrict__ y,
                       const float* __restrict__ z,
                       float* __restrict__ ws) {
    __shared__ float Gs[SLEN * 34];      // 33x34 gram tile; becomes inc tile in place
    __shared__ float Xi[SLEN * 8];
    __shared__ float Xj[SLEN * 8];

    const int g    = blockIdx.y;         // 0:rbf(x,x) 1:lin(y,y) 2:lin(z,z) 3:lin(y,z)
    const int lane = threadIdx.x;

    int gi, gj;
    if (g == 3) {
        gi = blockIdx.x >> 6;
        gj = blockIdx.x & 63;
    } else {
        // symmetric grams: lower triangle incl. diagonal, 2080 pairs
        int pair = blockIdx.x;
        if (pair >= 2080) return;
        float ff = sqrtf(8.0f * (float)pair + 1.0f);
        gi = (int)((ff - 1.0f) * 0.5f);
        while ((gi + 1) * (gi + 2) / 2 <= pair) ++gi;   // fix fp rounding
        while (gi * (gi + 1) / 2 > pair) --gi;
        gj = pair - gi * (gi + 1) / 2;
    }

    const float* Ap = (g == 0) ? x : ((g == 2) ? z : y);
    const float* Bp = (g == 0) ? x : ((g == 1) ? y : z);

    // Stage paths (vectorized: 264 floats = 66 float4 each)
    const float4* Asrc = (const float4*)(Ap + gi * (SLEN * 8));
    const float4* Bsrc = (const float4*)(Bp + gj * (SLEN * 8));
    float4* Xi4 = (float4*)Xi;
    float4* Xj4 = (float4*)Xj;
    for (int k = lane; k < SLEN * 2; k += 64) {
        Xi4[k] = Asrc[k];
        Xj4[k] = Bsrc[k];
    }
    __syncthreads();

    // Static-kernel 33x33 tile
    for (int idx = lane; idx < SLEN * SLEN; idx += 64) {
        int s = idx / SLEN;
        int t = idx - s * SLEN;
        float4 a0 = Xi4[s * 2], a1 = Xi4[s * 2 + 1];
        float4 b0 = Xj4[t * 2], b1 = Xj4[t * 2 + 1];
        float acc;
        if (g == 0) {
            float d0 = a0.x - b0.x, d1 = a0.y - b0.y, d2 = a0.z - b0.z, d3 = a0.w - b0.w;
            float d4 = a1.x - b1.x, d5 = a1.y - b1.y, d6 = a1.z - b1.z, d7 = a1.w - b1.w;
            acc = d0*d0 + d1*d1 + d2*d2 + d3*d3 + d4*d4 + d5*d5 + d6*d6 + d7*d7;
            acc = __expf(-acc);                       // sigma = 1
        } else {
            acc = a0.x*b0.x + a0.y*b0.y + a0.z*b0.z + a0.w*b0.w
                + a1.x*b1.x + a1.y*b1.y + a1.z*b1.z + a1.w*b1.w;
        }
        Gs[s * 34 + t] = acc;
    }
    __syncthreads();

    // In-place double increment, pre-scaled by 1/(f*f)=1/4.
    // Single wave: within a batch all 4 reads precede the write (value dep);
    // across batches writes trail reads (rows ascend). Safe in place.
    for (int idx = lane; idx < 32 * 32; idx += 64) {
        int s = idx >> 5, t = idx & 31;
        float g00 = Gs[s * 34 + t],      g01 = Gs[s * 34 + t + 1];
        float g10 = Gs[(s + 1) * 34 + t], g11 = Gs[(s + 1) * 34 + t + 1];
        Gs[s * 34 + t] = 0.25f * (g11 - g10 - g01 + g00);
    }
    __syncthreads();

    // Wavefront PDE: lane p computes cell (p, q=d-p) == k[p+1][q+1].
    //   k[p+1][q+1] = (k[p+1][q] + k[p][q+1])*c1 - k[p][q]*c2
    // left  = own v_cur (1.0 until active)
    // up    = neighbor's v_cur via shfl (1.0 boundary for lane 0)
    // diag  = previous step's 'up' (register carry — no second shfl)
    float v_cur = 1.0f, up_diag = 1.0f;
    const int rowbase = (lane >> 1) * 34;
    #pragma unroll 4
    for (int d = 0; d < 2 * PGRID - 1; ++d) {
        float up_c = __shfl_up(v_cur, 1);
        int q = d - lane;
        int t = q >> 1;
        t = t < 0 ? 0 : (t > 31 ? 31 : t);
        float inc = Gs[rowbase + t];
        float up = (lane == 0) ? 1.0f : up_c;
        float i2 = inc * inc * (1.0f / 12.0f);
        float c1 = 1.0f + 0.5f * inc + i2;
        float c2 = 1.0f - i2;
        float newv = (v_cur + up) * c1 - up_diag * c2;
        bool active = ((unsigned)q) < (unsigned)PGRID;
        v_cur = active ? newv : v_cur;
        up_diag = up;
    }

    if (lane == 63) {
        float* dst = ws + g * 4096;
        dst[gi * 64 + gj] = v_cur;
        if (g != 3) dst[gj * 64 + gi] = v_cur;   // mirror symmetric grams
    }
}

// ---------------------------------------------------------------------------
// Kernel B1: register-resident in-place Gauss-Jordan inverse of (K+I).
// One wave; lane c owns column c in 64 VGPRs. Cyclic rotation (fused into the
// update's write index) keeps the pivot row at static register index 0; the
// pivot column comes via __shfl(m[k], p). No LDS, no barriers.
// SPD => no pivoting needed. Kinv symmetric, so row/col-major equivalent.
// ---------------------------------------------------------------------------
__global__ __launch_bounds__(64)
void gj_inverse_kernel(float* __restrict__ ws) {
    const int lane = threadIdx.x;
    const float* K = ws;
    float* Kinv = ws + 4 * 4096;

    float m[64];
    #pragma unroll
    for (int r = 0; r < 64; ++r)
        m[r] = K[r * 64 + lane] + ((r == lane) ? 1.0f : 0.0f);   // K + I

    #pragma unroll 1
    for (int p = 0; p < 64; ++p) {
        // invariant: physical reg k holds row (k+p) mod 64; m[0] = pivot row p
        float piv  = __shfl(m[0], p);          // A[p][p]
        float dinv = 1.0f / piv;
        float sp   = (lane == p) ? dinv : m[0] * dinv;   // scaled pivot row
        #pragma unroll
        for (int k = 1; k < 64; ++k) {
            float fac = __shfl(m[k], p);       // A[r][p], r=(k+p)%64
            float v = fmaf(-fac, sp, m[k]);    // A[r][c] -= fac * sp
            v = (lane == p) ? (-fac * dinv) : v;   // column-p entry
            m[k - 1] = v;                      // rotate: row r -> slot k-1
        }
        m[63] = sp;                            // pivot row -> slot 63
    }
    // after 64 steps rotation is identity: m[r] = Kinv[r][lane]
    #pragma unroll
    for (int r = 0; r < 64; ++r)
        Kinv[r * 64 + lane] = m[r];
}

// ---------------------------------------------------------------------------
// Kernel B2: block i computes row i of W = Kinv K Kinv, dotted with L[:,i].
// ---------------------------------------------------------------------------
__global__ __launch_bounds__(64)
void trace_partial_kernel(const float* __restrict__ ws, float* __restrict__ partial) {
    const int i    = blockIdx.x;
    const int lane = threadIdx.x;
    const float* K    = ws;
    const float* Lg   = ws + 4096;
    const float* Lt   = ws + 8192;
    const float* Lm   = ws + 12288;
    const float* Kinv = ws + 16384;

    // u_j = (Kinv K)[i][j] : scalar-broadcast Kinv row, coalesced K rows
    float u = 0.0f;
    #pragma unroll 8
    for (int k = 0; k < 64; ++k)
        u = fmaf(Kinv[i * 64 + k], K[k * 64 + lane], u);

    // w_j = W[i][j] = sum_k u_k Kinv[k][j] : u broadcast via shfl
    float w = 0.0f;
    #pragma unroll 8
    for (int k = 0; k < 64; ++k)
        w = fmaf(__shfl(u, k), Kinv[k * 64 + lane], w);

    float lc = Lg[lane * 64 + i] + Lt[lane * 64 + i] - 2.0f * Lm[lane * 64 + i];
    float local = w * lc;
    #pragma unroll
    for (int off = 32; off > 0; off >>= 1)
        local += __shfl_down(local, off);
    if (lane == 0) partial[i] = local;
}

__global__ __launch_bounds__(64)
void final_sum_kernel(const float* __restrict__ partial, float* __restrict__ out) {
    float v = partial[threadIdx.x];
    #pragma unroll
    for (int off = 32; off > 0; off >>= 1)
        v += __shfl_down(v, off);
    if (threadIdx.x == 0) out[0] = v;
}

extern "C" void kernel_launch(void* const* d_in, const int* in_sizes, int n_in,
                              void* d_out, int out_size, void* d_ws, size_t ws_size,
                              hipStream_t stream) {
    const float* x = (const float*)d_in[0];
    const float* y = (const float*)d_in[1];
    const float* z = (const float*)d_in[2];
    float* out = (float*)d_out;
    float* ws  = (float*)d_ws;      // needs 20544 floats ≈ 80.3 KB

    dim3 gridA(4096, 4);
    sigker_pde_kernel<<<gridA, 64, 0, stream>>>(x, y, z, ws);
    gj_inverse_kernel<<<1, 64, 0, stream>>>(ws);
    trace_partial_kernel<<<64, 64, 0, stream>>>(ws, ws + 5 * 4096);
    final_sum_kernel<<<1, 64, 0, stream>>>(ws + 5 * 4096, out);
}

// Round 3
// 175.336 us; speedup vs baseline: 2.2501x; 1.0446x over previous
//
#include <hip/hip_runtime.h>
#include <math.h>

// ConditionalSigKerMMDDiscriminator — x,y,z: (64,33,8) fp32 -> scalar fp32.
//
//   K      = sigker(rbf(x,x))   [symmetric]
//   L_gen  = sigker(lin(y,y))   [symmetric]
//   L_true = sigker(lin(z,z))   [symmetric]
//   L_mix  = sigker(lin(y,z))   [full]
//   Kinv   = (K+I)^-1;  K*Kinv = I - Kinv  =>  W = Kinv K Kinv = Kinv - Kinv^2
//   out    = sum_ij W[i][j] * (Lg + Lt - 2 Lm)[j][i]
//
// ws layout (floats): [0]=K [4096]=Lg [8192]=Lt [12288]=Lm [16384]=Kinv [20480]=partial(64)

#define SLEN 33

// ---------------------------------------------------------------------------
// Kernel A: 2x2-block wavefront PDE. One wave = 2 pairs (lane halves).
// Lane p (=lane&31) owns block-row p (grid rows 2p, 2p+1). 63 diagonal steps,
// 4 cells/step, one inc value per step (dyadic f=2: 2x2 cells share inc[p][t]).
// grid = 5168 1D: [0,1040) g0 rbf(x,x) tri; [1040,2080) g1; [2080,3120) g2;
// [3120,5168) g3 lin(y,z) full.
// ---------------------------------------------------------------------------
__global__ __launch_bounds__(64, 4)
void sigker_pde_kernel(const float* __restrict__ x,
                       const float* __restrict__ y,
                       const float* __restrict__ z,
                       float* __restrict__ ws) {
    __shared__ float Xi[2][264];
    __shared__ float Xj[2][264];
    __shared__ float G[2][1089];   // 33x33 stride-33 gram; overlaid by 32x32 stride-32 inc

    const int lane = threadIdx.x;
    const int h = lane >> 5;       // which pair in this wave
    const int p = lane & 31;       // block-row

    int b = blockIdx.x;
    int g, loc;
    if (b < 1040)      { g = 0; loc = b; }
    else if (b < 2080) { g = 1; loc = b - 1040; }
    else if (b < 3120) { g = 2; loc = b - 2080; }
    else               { g = 3; loc = b - 3120; }

    int pair = 2 * loc + h;
    int gi, gj;
    if (g == 3) {
        gi = pair >> 6; gj = pair & 63;
    } else {
        // lower-triangle (incl diag) decode of pair in [0,2080)
        float ff = sqrtf(8.0f * (float)pair + 1.0f);
        gi = (int)((ff - 1.0f) * 0.5f);
        while ((gi + 1) * (gi + 2) / 2 <= pair) ++gi;
        while (gi * (gi + 1) / 2 > pair) --gi;
        gj = pair - gi * (gi + 1) / 2;
    }

    const float* Ap = (g == 0) ? x : ((g == 2) ? z : y);
    const float* Bp = (g == 0) ? x : ((g == 1) ? y : z);

    // Stage the two paths for this half's pair (66 float4 each)
    const float4* As = (const float4*)(Ap + gi * (SLEN * 8));
    const float4* Bs = (const float4*)(Bp + gj * (SLEN * 8));
    float4* Xi4 = (float4*)Xi[h];
    float4* Xj4 = (float4*)Xj[h];
    for (int k = p; k < 66; k += 32) { Xi4[k] = As[k]; Xj4[k] = Bs[k]; }
    __syncthreads();

    // 33x33 static-kernel tile, stride 33
    float* Gh = G[h];
    for (int idx = p; idx < SLEN * SLEN; idx += 32) {
        int s = idx / 33;
        int t = idx - s * 33;
        float4 a0 = Xi4[2 * s], a1 = Xi4[2 * s + 1];
        float4 b0 = Xj4[2 * t], b1 = Xj4[2 * t + 1];
        float acc;
        if (g == 0) {
            float d0 = a0.x - b0.x, d1 = a0.y - b0.y, d2 = a0.z - b0.z, d3 = a0.w - b0.w;
            float d4 = a1.x - b1.x, d5 = a1.y - b1.y, d6 = a1.z - b1.z, d7 = a1.w - b1.w;
            acc = d0*d0 + d1*d1 + d2*d2 + d3*d3 + d4*d4 + d5*d5 + d6*d6 + d7*d7;
            acc = __expf(-acc);                       // sigma = 1
        } else {
            acc = a0.x*b0.x + a0.y*b0.y + a0.z*b0.z + a0.w*b0.w
                + a1.x*b1.x + a1.y*b1.y + a1.z*b1.z + a1.w*b1.w;
        }
        Gh[idx] = acc;
    }
    __syncthreads();

    // Double increment / 4, overlaid into the same buffer at stride 32.
    // Lane p handles column p of all 32 inc rows; values buffered in regs
    // across a barrier so reads (stride 33) never race writes (stride 32).
    float vreg[32];
    {
        float ga = Gh[p], gb = Gh[p + 1];
        #pragma unroll
        for (int k = 0; k < 32; ++k) {
            float gc = Gh[(k + 1) * 33 + p];
            float gd = Gh[(k + 1) * 33 + p + 1];
            vreg[k] = 0.25f * (gd - gc - gb + ga);
            ga = gc; gb = gd;
        }
    }
    __syncthreads();
    #pragma unroll
    for (int k = 0; k < 32; ++k)
        Gh[k * 32 + p] = vreg[k];
    __syncthreads();

    // 2x2-block anti-diagonal wavefront. At step m, lane p computes block
    // (p, t=m-p): cells c00=(2p,2t) c01=(2p,2t+1) c10=(2p+1,2t) c11=(2p+1,2t+1),
    // all sharing inc[p][t]. Neighbor row data via 2 shfls; diag via carry.
    float c01 = 1.0f, c10 = 1.0f, c11 = 1.0f, dcarry = 1.0f;
    const bool isrow0 = (p == 0);
    for (int m = 0; m < 63; ++m) {
        float nb10 = __shfl_up(c10, 1);
        float nb11 = __shfl_up(c11, 1);
        int t = m - p;
        float incv = Gh[p * 32 + (t & 31)];
        float n0 = isrow0 ? 1.0f : nb10;     // cell(2p-1, 2t)
        float n1 = isrow0 ? 1.0f : nb11;     // cell(2p-1, 2t+1)
        bool t0 = (t == 0);
        float w0 = t0 ? 1.0f : c01;          // cell(2p,   2t-1)
        float w1 = t0 ? 1.0f : c11;          // cell(2p+1, 2t-1)
        float d  = t0 ? 1.0f : dcarry;       // cell(2p-1, 2t-1)
        float i2 = incv * incv * (1.0f / 12.0f);
        float C1 = 1.0f + 0.5f * incv + i2;
        float C2 = 1.0f - i2;
        float v00 = (w0  + n0 ) * C1 - d   * C2;
        float v01 = (v00 + n1 ) * C1 - n0  * C2;
        float v10 = (v00 + w1 ) * C1 - w0  * C2;
        float v11 = (v10 + v01) * C1 - v00 * C2;
        bool act = ((unsigned)t) < 32u;
        c01 = act ? v01 : c01;
        c10 = act ? v10 : c10;
        c11 = act ? v11 : c11;
        dcarry = n1;
    }

    if (p == 31) {   // lane holding cell (63,63)
        float* dst = ws + g * 4096;
        dst[gi * 64 + gj] = c11;
        if (g != 3) dst[gj * 64 + gi] = c11;
    }
}

// ---------------------------------------------------------------------------
// Kernel B1: register-resident in-place Gauss-Jordan inverse of (K+I).
// One wave; lane c owns column c. launch_bounds(64,1) => full VGPR budget,
// m[64] stays in registers (round-2 spilled at the default occupancy target).
// ---------------------------------------------------------------------------
__global__ __launch_bounds__(64, 1)
void gj_inverse_kernel(float* __restrict__ ws) {
    const int lane = threadIdx.x;
    const float* K = ws;
    float* Kinv = ws + 4 * 4096;

    float m[64];
    #pragma unroll
    for (int r = 0; r < 64; ++r)
        m[r] = K[r * 64 + lane] + ((r == lane) ? 1.0f : 0.0f);   // K + I

    #pragma unroll 1
    for (int p = 0; p < 64; ++p) {
        // invariant: physical slot k holds row (k+p) mod 64; m[0] = pivot row
        float piv  = __shfl(m[0], p);
        float dinv = 1.0f / piv;
        float sp   = (lane == p) ? dinv : m[0] * dinv;
        #pragma unroll
        for (int k = 1; k < 64; ++k) {
            float fac = __shfl(m[k], p);
            float v = fmaf(-fac, sp, m[k]);
            v = (lane == p) ? (-fac * dinv) : v;
            m[k - 1] = v;
        }
        m[63] = sp;
    }
    #pragma unroll
    for (int r = 0; r < 64; ++r)
        Kinv[r * 64 + lane] = m[r];
}

// ---------------------------------------------------------------------------
// Kernel B2: block i computes W[i][:] = Kinv[i][:] - (Kinv^2)[i][:],
// dotted with L[:,i].  (One matmul pass saved via K*Kinv = I - Kinv.)
// ---------------------------------------------------------------------------
__global__ __launch_bounds__(64)
void trace_partial_kernel(const float* __restrict__ ws, float* __restrict__ partial) {
    const int i    = blockIdx.x;
    const int lane = threadIdx.x;
    const float* Lg   = ws + 4096;
    const float* Lt   = ws + 8192;
    const float* Lm   = ws + 12288;
    const float* Kinv = ws + 16384;

    float u = Kinv[i * 64 + lane];          // Kinv[i][lane]
    float acc = 0.0f;
    #pragma unroll 8
    for (int k = 0; k < 64; ++k)
        acc = fmaf(__shfl(u, k), Kinv[k * 64 + lane], acc);   // (Kinv^2)[i][lane]
    float w = u - acc;

    float lc = Lg[lane * 64 + i] + Lt[lane * 64 + i] - 2.0f * Lm[lane * 64 + i];
    float local = w * lc;
    #pragma unroll
    for (int off = 32; off > 0; off >>= 1)
        local += __shfl_down(local, off);
    if (lane == 0) partial[i] = local;
}

__global__ __launch_bounds__(64)
void final_sum_kernel(const float* __restrict__ partial, float* __restrict__ out) {
    float v = partial[threadIdx.x];
    #pragma unroll
    for (int off = 32; off > 0; off >>= 1)
        v += __shfl_down(v, off);
    if (threadIdx.x == 0) out[0] = v;
}

extern "C" void kernel_launch(void* const* d_in, const int* in_sizes, int n_in,
                              void* d_out, int out_size, void* d_ws, size_t ws_size,
                              hipStream_t stream) {
    const float* x = (const float*)d_in[0];
    const float* y = (const float*)d_in[1];
    const float* z = (const float*)d_in[2];
    float* out = (float*)d_out;
    float* ws  = (float*)d_ws;      // 20544 floats ≈ 80.3 KB used

    sigker_pde_kernel<<<5168, 64, 0, stream>>>(x, y, z, ws);
    gj_inverse_kernel<<<1, 64, 0, stream>>>(ws);
    trace_partial_kernel<<<64, 64, 0, stream>>>(ws, ws + 5 * 4096);
    final_sum_kernel<<<1, 64, 0, stream>>>(ws + 5 * 4096, out);
}

// Round 4
// 172.315 us; speedup vs baseline: 2.2895x; 1.0175x over previous
//
#include <hip/hip_runtime.h>
#include <math.h>

// ConditionalSigKerMMDDiscriminator — x,y,z: (64,33,8) fp32 -> scalar fp32.
//
//   K      = sigker(rbf(x,x))   [symmetric]
//   L_gen  = sigker(lin(y,y))   [symmetric]
//   L_true = sigker(lin(z,z))   [symmetric]
//   L_mix  = sigker(lin(y,z))   [full]
//   Kinv   = (K+I)^-1;  K*Kinv = I - Kinv  =>  W = Kinv - Kinv^2 (symmetric)
//   out    = sum_ij W[i][j]*(Lg+Lt-2Lm)[j][i] = sum_ij W[i][j]*Lc[i][j]
//
// ws layout (floats): [0]=K [4096]=Lg [8192]=Lt [12288]=Lm

#define SLEN 33

// ---------------------------------------------------------------------------
// Kernel A: 2x2-block wavefront PDE. One wave = 2 pairs (lane halves).
// Lane p (=lane&31) owns block-row p. 63 diagonal steps, 4 cells/step.
// Linear grams skip the Gram tile: inc[s][t] = dXi[s]·dXj[t]/4 directly.
// inc layout GI[k*32+p] = inc[k][p]: writes bank=p, wavefront reads bank=(m-p)
// -> both conflict-free (verified round 3: SQ_LDS_BANK_CONFLICT=0).
// grid = 5168: [0,1040) rbf(x,x) tri; +1040 lin(y,y) tri; +1040 lin(z,z) tri;
// [3120,5168) lin(y,z) full.
// ---------------------------------------------------------------------------
__global__ __launch_bounds__(64, 4)
void sigker_pde_kernel(const float* __restrict__ x,
                       const float* __restrict__ y,
                       const float* __restrict__ z,
                       float* __restrict__ ws) {
    __shared__ float4 Xi4[2][66];
    __shared__ float4 Xj4[2][66];
    __shared__ float GI[2][1089];   // rbf: 33x33 gram (stride 33) then overlaid
                                    // 32x32 inc (stride 32); linear: inc only

    const int lane = threadIdx.x;
    const int h = lane >> 5;        // which pair in this wave
    const int p = lane & 31;        // block-row

    int b = blockIdx.x, g, loc;
    if (b < 1040)      { g = 0; loc = b; }
    else if (b < 2080) { g = 1; loc = b - 1040; }
    else if (b < 3120) { g = 2; loc = b - 2080; }
    else               { g = 3; loc = b - 3120; }

    int pair = 2 * loc + h, gi, gj;
    if (g == 3) {
        gi = pair >> 6; gj = pair & 63;
    } else {
        float ff = sqrtf(8.0f * (float)pair + 1.0f);
        gi = (int)((ff - 1.0f) * 0.5f);
        while ((gi + 1) * (gi + 2) / 2 <= pair) ++gi;
        while (gi * (gi + 1) / 2 > pair) --gi;
        gj = pair - gi * (gi + 1) / 2;
    }

    const float* Ap = (g == 0) ? x : ((g == 2) ? z : y);
    const float* Bp = (g == 0) ? x : ((g == 1) ? y : z);
    const float4* As = (const float4*)(Ap + gi * (SLEN * 8));
    const float4* Bs = (const float4*)(Bp + gj * (SLEN * 8));
    for (int k = p; k < 66; k += 32) { Xi4[h][k] = As[k]; Xj4[h][k] = Bs[k]; }
    __syncthreads();

    if (g == 0) {
        // RBF: build 33x33 gram, then double-diff into stride-32 overlay
        for (int idx = p; idx < SLEN * SLEN; idx += 32) {
            int s = idx / 33, t = idx - s * 33;
            float4 a0 = Xi4[h][2*s], a1 = Xi4[h][2*s+1];
            float4 b0 = Xj4[h][2*t], b1 = Xj4[h][2*t+1];
            float d0 = a0.x-b0.x, d1 = a0.y-b0.y, d2 = a0.z-b0.z, d3 = a0.w-b0.w;
            float d4 = a1.x-b1.x, d5 = a1.y-b1.y, d6 = a1.z-b1.z, d7 = a1.w-b1.w;
            float acc = d0*d0+d1*d1+d2*d2+d3*d3+d4*d4+d5*d5+d6*d6+d7*d7;
            GI[h][idx] = __expf(-acc);        // sigma = 1
        }
        __syncthreads();
        // lane p computes inc column p; register-buffered across a barrier
        float vreg[32];
        float ga = GI[h][p], gb = GI[h][p + 1];
        #pragma unroll
        for (int k = 0; k < 32; ++k) {
            float gc = GI[h][(k+1)*33 + p], gd = GI[h][(k+1)*33 + p + 1];
            vreg[k] = 0.25f * (gd - gc - gb + ga);
            ga = gc; gb = gd;
        }
        __syncthreads();
        #pragma unroll
        for (int k = 0; k < 32; ++k)
            GI[h][k*32 + p] = vreg[k];
    } else {
        // Linear: inc[k][p] = (Xi[k+1]-Xi[k])·(Xj[p+1]-Xj[p]) / 4, no gram.
        float4 b0 = Xj4[h][2*p],   b1 = Xj4[h][2*p+1];
        float4 b2 = Xj4[h][2*p+2], b3 = Xj4[h][2*p+3];
        float e0 = b2.x-b0.x, e1 = b2.y-b0.y, e2 = b2.z-b0.z, e3 = b2.w-b0.w;
        float e4 = b3.x-b1.x, e5 = b3.y-b1.y, e6 = b3.z-b1.z, e7 = b3.w-b1.w;
        float4 a0 = Xi4[h][0], a1 = Xi4[h][1];
        #pragma unroll 4
        for (int k = 0; k < 32; ++k) {
            float4 a2 = Xi4[h][2*k+2], a3 = Xi4[h][2*k+3];   // broadcast reads
            float acc = (a2.x-a0.x)*e0 + (a2.y-a0.y)*e1
                      + (a2.z-a0.z)*e2 + (a2.w-a0.w)*e3
                      + (a3.x-a1.x)*e4 + (a3.y-a1.y)*e5
                      + (a3.z-a1.z)*e6 + (a3.w-a1.w)*e7;
            GI[h][k*32 + p] = 0.25f * acc;
            a0 = a2; a1 = a3;
        }
    }
    __syncthreads();

    // 2x2-block anti-diagonal wavefront (round-3 verified).
    float c01 = 1.0f, c10 = 1.0f, c11 = 1.0f, dcarry = 1.0f;
    const bool isrow0 = (p == 0);
    const float* incrow = &GI[h][p * 32];
    for (int m = 0; m < 63; ++m) {
        float nb10 = __shfl_up(c10, 1);
        float nb11 = __shfl_up(c11, 1);
        int t = m - p;
        float incv = incrow[t & 31];
        float n0 = isrow0 ? 1.0f : nb10;
        float n1 = isrow0 ? 1.0f : nb11;
        bool t0 = (t == 0);
        float w0 = t0 ? 1.0f : c01;
        float w1 = t0 ? 1.0f : c11;
        float d  = t0 ? 1.0f : dcarry;
        float i2 = incv * incv * (1.0f / 12.0f);
        float C1 = 1.0f + 0.5f * incv + i2;
        float C2 = 1.0f - i2;
        float v00 = (w0  + n0 ) * C1 - d   * C2;
        float v01 = (v00 + n1 ) * C1 - n0  * C2;
        float v10 = (v00 + w1 ) * C1 - w0  * C2;
        float v11 = (v10 + v01) * C1 - v00 * C2;
        bool act = ((unsigned)t) < 32u;
        c01 = act ? v01 : c01;
        c10 = act ? v10 : c10;
        c11 = act ? v11 : c11;
        dcarry = n1;
    }

    if (p == 31) {
        float* dst = ws + g * 4096;
        dst[gi * 64 + gj] = c11;
        if (g != 3) dst[gj * 64 + gi] = c11;
    }
}

// ---------------------------------------------------------------------------
// Kernel B (fused): Gauss-Jordan inverse of (K+I) with rows in REGISTERS
// (thread (w=tid>>6, c=tid&63) owns Kinv[w*16+i][c] in m[16] — small static
// array, no scratch), then trace in the same block.
// Per pivot: pivot wave publishes scaled pivot row to ping-pong LDS row
// (1 barrier/pivot); fac via intra-wave __shfl(m[i], p).
// ---------------------------------------------------------------------------
__global__ __launch_bounds__(256, 1)
void final_fused_kernel(const float* __restrict__ ws, float* __restrict__ out) {
    __shared__ float prow[2][64];
    __shared__ float Kls[64 * 65];
    __shared__ float red[256];

    const int tid = threadIdx.x;
    const int c = tid & 63, w = tid >> 6;
    const float* K  = ws;
    const float* Lg = ws + 4096;
    const float* Lt = ws + 8192;
    const float* Lm = ws + 12288;

    float m[16];
    #pragma unroll
    for (int i = 0; i < 16; ++i) {
        int r = w * 16 + i;
        m[i] = K[r * 64 + c] + ((r == c) ? 1.0f : 0.0f);   // K + I
    }

    #pragma unroll 1
    for (int p = 0; p < 64; ++p) {
        const int wp = p >> 4, ip = p & 15, buf = p & 1;
        if (w == wp) {
            #pragma unroll
            for (int i = 0; i < 16; ++i) {
                if (i == ip) {                      // static index, uniform branch
                    float piv  = __shfl(m[i], p);   // A[p][p]
                    float dinv = 1.0f / piv;
                    float spv  = (c == p) ? dinv : m[i] * dinv;
                    prow[buf][c] = spv;
                    m[i] = spv;                     // pivot row done
                }
            }
        }
        __syncthreads();
        float spv  = prow[buf][c];
        float dinv = prow[buf][p];                  // = 1/piv (broadcast)
        #pragma unroll
        for (int i = 0; i < 16; ++i) {
            bool pivotRow = (w == wp) && (i == ip);
            float fac = __shfl(m[i], p);            // A[r_i][p]
            float nv  = (c == p) ? (-fac * dinv) : fmaf(-fac, spv, m[i]);
            if (!pivotRow) m[i] = nv;
        }
        // next pivot writes prow[buf^1]; barrier at next iter separates reuse
    }

    // m[i] = Kinv[w*16+i][c].  Stage to LDS for the Kinv^2 pass.
    #pragma unroll
    for (int i = 0; i < 16; ++i)
        Kls[(w * 16 + i) * 65 + c] = m[i];
    __syncthreads();

    // acc[i] = (Kinv^2)[w*16+i][c]
    float acc[16];
    #pragma unroll
    for (int i = 0; i < 16; ++i) acc[i] = 0.0f;
    #pragma unroll 1
    for (int k = 0; k < 64; ++k) {
        float rv = Kls[k * 65 + c];                 // row read, conflict-free
        #pragma unroll
        for (int i = 0; i < 16; ++i)
            acc[i] = fmaf(Kls[(w * 16 + i) * 65 + k], rv, acc[i]);  // broadcast
    }

    // W = Kinv - Kinv^2 is symmetric => tr(W L) = sum W[r][c]*Lc[r][c]
    float local = 0.0f;
    #pragma unroll
    for (int i = 0; i < 16; ++i) {
        int r = w * 16 + i;
        float lc = Lg[r * 64 + c] + Lt[r * 64 + c] - 2.0f * Lm[r * 64 + c];
        local += (m[i] - acc[i]) * lc;
    }
    red[tid] = local;
    __syncthreads();
    if (tid < 128) red[tid] += red[tid + 128];
    __syncthreads();
    if (tid < 64) {
        float v = red[tid] + red[tid + 64];
        #pragma unroll
        for (int off = 32; off > 0; off >>= 1)
            v += __shfl_down(v, off);
        if (tid == 0) out[0] = v;
    }
}

extern "C" void kernel_launch(void* const* d_in, const int* in_sizes, int n_in,
                              void* d_out, int out_size, void* d_ws, size_t ws_size,
                              hipStream_t stream) {
    const float* x = (const float*)d_in[0];
    const float* y = (const float*)d_in[1];
    const float* z = (const float*)d_in[2];
    float* out = (float*)d_out;
    float* ws  = (float*)d_ws;      // 16384 floats = 64 KB used

    sigker_pde_kernel<<<5168, 64, 0, stream>>>(x, y, z, ws);
    final_fused_kernel<<<1, 256, 0, stream>>>(ws, out);
}

// Round 5
// 130.204 us; speedup vs baseline: 3.0300x; 1.3234x over previous
//
#include <hip/hip_runtime.h>
#include <hip/hip_fp16.h>
#include <math.h>

// ConditionalSigKerMMDDiscriminator — x,y,z: (64,33,8) fp32 -> scalar fp32.
//
//   K      = sigker(rbf(x,x))   [symmetric]
//   L_gen  = sigker(lin(y,y))   [symmetric]
//   L_true = sigker(lin(z,z))   [symmetric]
//   L_mix  = sigker(lin(y,z))   [full]
//   Kinv   = (K+I)^-1;  K*Kinv = I - Kinv  =>  W = Kinv - Kinv^2 (symmetric)
//   out    = sum_ij W[i][j]*(Lg+Lt-2Lm)[j][i]
//
// ws floats: [0]=K [4096]=Lg [8192]=Lt [12288]=Lm [16384]=Kinv [20480]=partial

#define SLEN 33

// ---------------------------------------------------------------------------
// Kernel A: 2x2-block wavefront PDE. One wave = 2 pairs (lane halves).
// LDS per block: Xi stage 2x1056B + fp16 inc 2x2048B = 6.2 KB -> ~20 blocks/CU
// resident (single generation for the 5168-block grid).
// inc half-precision: |inc| ~ 1e-2, rel err 5e-4 -> ~1e-4 on L entries,
// far inside the 0.149 output budget.
// ---------------------------------------------------------------------------
__global__ __launch_bounds__(64, 5)
void sigker_pde_kernel(const float* __restrict__ x,
                       const float* __restrict__ y,
                       const float* __restrict__ z,
                       float* __restrict__ ws) {
    __shared__ float4 Xi4[2][66];
    __shared__ __half incH[2][1024];   // inc[row][col], row-major stride 32

    const int lane = threadIdx.x;
    const int h = lane >> 5;        // which pair in this wave
    const int p = lane & 31;        // block-row / build-column

    int b = blockIdx.x, g, loc;
    if (b < 1040)      { g = 0; loc = b; }
    else if (b < 2080) { g = 1; loc = b - 1040; }
    else if (b < 3120) { g = 2; loc = b - 2080; }
    else               { g = 3; loc = b - 3120; }

    int pair = 2 * loc + h, gi, gj;
    if (g == 3) {
        gi = pair >> 6; gj = pair & 63;
    } else {
        float ff = sqrtf(8.0f * (float)pair + 1.0f);
        gi = (int)((ff - 1.0f) * 0.5f);
        while ((gi + 1) * (gi + 2) / 2 <= pair) ++gi;
        while (gi * (gi + 1) / 2 > pair) --gi;
        gj = pair - gi * (gi + 1) / 2;
    }

    const float* Ap = (g == 0) ? x : ((g == 2) ? z : y);
    const float* Bp = (g == 0) ? x : ((g == 1) ? y : z);
    const float4* As = (const float4*)(Ap + gi * (SLEN * 8));
    const float4* Bs = (const float4*)(Bp + gj * (SLEN * 8));

    // Stage Xi (broadcast-read later); Xj rows p, p+1 live in registers.
    for (int k = p; k < 66; k += 32) Xi4[h][k] = As[k];
    float4 b0 = Bs[2*p],   b1 = Bs[2*p+1];
    float4 b2 = Bs[2*p+2], b3 = Bs[2*p+3];
    __syncthreads();

    if (g == 0) {
        // RBF: lane p slides down gram columns p and p+1; no gram tile.
        // inc[k-1][p] = 0.25*(diff_k - diff_{k-1}), diff_k = G[k][p+1]-G[k][p]
        float nprev;
        {
            float4 a0 = Xi4[h][0], a1 = Xi4[h][1];
            float d0=a0.x-b0.x,d1=a0.y-b0.y,d2=a0.z-b0.z,d3=a0.w-b0.w;
            float d4=a1.x-b1.x,d5=a1.y-b1.y,d6=a1.z-b1.z,d7=a1.w-b1.w;
            float da = d0*d0+d1*d1+d2*d2+d3*d3+d4*d4+d5*d5+d6*d6+d7*d7;
            float e0=a0.x-b2.x,e1=a0.y-b2.y,e2=a0.z-b2.z,e3=a0.w-b2.w;
            float e4=a1.x-b3.x,e5=a1.y-b3.y,e6=a1.z-b3.z,e7=a1.w-b3.w;
            float db = e0*e0+e1*e1+e2*e2+e3*e3+e4*e4+e5*e5+e6*e6+e7*e7;
            nprev = __expf(-db) - __expf(-da);
        }
        for (int k = 1; k <= 32; ++k) {
            float4 a0 = Xi4[h][2*k], a1 = Xi4[h][2*k+1];
            float d0=a0.x-b0.x,d1=a0.y-b0.y,d2=a0.z-b0.z,d3=a0.w-b0.w;
            float d4=a1.x-b1.x,d5=a1.y-b1.y,d6=a1.z-b1.z,d7=a1.w-b1.w;
            float da = d0*d0+d1*d1+d2*d2+d3*d3+d4*d4+d5*d5+d6*d6+d7*d7;
            float e0=a0.x-b2.x,e1=a0.y-b2.y,e2=a0.z-b2.z,e3=a0.w-b2.w;
            float e4=a1.x-b3.x,e5=a1.y-b3.y,e6=a1.z-b3.z,e7=a1.w-b3.w;
            float db = e0*e0+e1*e1+e2*e2+e3*e3+e4*e4+e5*e5+e6*e6+e7*e7;
            float diffk = __expf(-db) - __expf(-da);
            incH[h][(k-1)*32 + p] = __float2half(0.25f * (diffk - nprev));
            nprev = diffk;
        }
    } else {
        // Linear: inc[k][p] = dXi[k]·dXj[p] / 4 (rank-1, no gram).
        float e0=b2.x-b0.x, e1=b2.y-b0.y, e2=b2.z-b0.z, e3=b2.w-b0.w;
        float e4=b3.x-b1.x, e5=b3.y-b1.y, e6=b3.z-b1.z, e7=b3.w-b1.w;
        float4 a0 = Xi4[h][0], a1 = Xi4[h][1];
        #pragma unroll 4
        for (int k = 0; k < 32; ++k) {
            float4 a2 = Xi4[h][2*k+2], a3 = Xi4[h][2*k+3];
            float acc = (a2.x-a0.x)*e0 + (a2.y-a0.y)*e1
                      + (a2.z-a0.z)*e2 + (a2.w-a0.w)*e3
                      + (a3.x-a1.x)*e4 + (a3.y-a1.y)*e5
                      + (a3.z-a1.z)*e6 + (a3.w-a1.w)*e7;
            incH[h][k*32 + p] = __float2half(0.25f * acc);
            a0 = a2; a1 = a3;
        }
    }
    __syncthreads();

    // 2x2-block anti-diagonal wavefront (structure verified rounds 3-4).
    // Unmasked updates: at t==0 all inputs are forced to boundary 1.0, so
    // pre-entry garbage never propagates; lane p's post-t=31 garbage is
    // never read (lane p+1's last shfl consumes lane p's t=31 state).
    float c01 = 1.0f, c10 = 1.0f, c11 = 1.0f, dcarry = 1.0f;
    const bool isrow0 = (p == 0);
    const __half* incrow = &incH[h][p * 32];
    #pragma unroll 4
    for (int m = 0; m < 63; ++m) {
        float nb10 = __shfl_up(c10, 1);
        float nb11 = __shfl_up(c11, 1);
        int t = m - p;
        float incv = __half2float(incrow[t & 31]);
        float n0 = isrow0 ? 1.0f : nb10;
        float n1 = isrow0 ? 1.0f : nb11;
        bool t0 = (t == 0);
        float w0 = t0 ? 1.0f : c01;
        float w1 = t0 ? 1.0f : c11;
        float d  = t0 ? 1.0f : dcarry;
        float i2 = incv * incv * (1.0f / 12.0f);
        float C1 = 1.0f + 0.5f * incv + i2;
        float C2 = 1.0f - i2;
        float v00 = (w0  + n0 ) * C1 - d   * C2;
        float v01 = (v00 + n1 ) * C1 - n0  * C2;
        float v10 = (v00 + w1 ) * C1 - w0  * C2;
        float v11 = (v10 + v01) * C1 - v00 * C2;
        c01 = v01; c10 = v10; c11 = v11;
        dcarry = n1;
    }

    if (p == 31) {
        float* dst = ws + g * 4096;
        dst[gi * 64 + gj] = c11;
        if (g != 3) dst[gj * 64 + gi] = c11;
    }
}

// ---------------------------------------------------------------------------
// Kernel B1: 2x2-block Gauss-Jordan inverse of (K+I), rows in registers
// (thread (w=tid>>6,c=tid&63) owns rows w*16+i). 32 barrier rounds instead
// of 64. Outer loop over pivot-owning wave wp, inner 8 rounds fully
// unrolled so every m[] index is compile-time (no scratch — round-4 proof).
// ---------------------------------------------------------------------------
__global__ __launch_bounds__(256, 1)
void gj_inverse_kernel(float* __restrict__ ws) {
    __shared__ float prow[2][2][64];
    const int tid = threadIdx.x;
    const int c = tid & 63, w = tid >> 6;
    const float* K = ws;
    float* Kinv = ws + 16384;

    float m[16];
    #pragma unroll
    for (int i = 0; i < 16; ++i) {
        int r = w * 16 + i;
        m[i] = K[r * 64 + c] + ((r == c) ? 1.0f : 0.0f);   // K + I
    }

    #pragma unroll 1
    for (int wp = 0; wp < 4; ++wp) {
        #pragma unroll
        for (int rr = 0; rr < 8; ++rr) {
            const int p0 = wp * 16 + 2 * rr, p1 = p0 + 1;
            const int i0 = 2 * rr, i1 = i0 + 1;      // compile-time
            const int buf = rr & 1;
            if (w == wp) {
                // 2x2 pivot block inverse (SPD principal block, det>0)
                float a  = __shfl(m[i0], p0), bq = __shfl(m[i0], p1);
                float cq = __shfl(m[i1], p0), dq = __shfl(m[i1], p1);
                float dinv = 1.0f / (a * dq - bq * cq);
                float P00 =  dq * dinv, P01 = -bq * dinv;
                float P10 = -cq * dinv, P11 =  a  * dinv;
                float sp0 = P00 * m[i0] + P01 * m[i1];
                float sp1 = P10 * m[i0] + P11 * m[i1];
                sp0 = (c == p0) ? P00 : ((c == p1) ? P01 : sp0);
                sp1 = (c == p0) ? P10 : ((c == p1) ? P11 : sp1);
                m[i0] = sp0; m[i1] = sp1;
                prow[buf][0][c] = sp0;
                prow[buf][1][c] = sp1;
            }
            __syncthreads();
            float s0 = prow[buf][0][c],  s1 = prow[buf][1][c];
            float q00 = prow[buf][0][p0], q01 = prow[buf][0][p1];
            float q10 = prow[buf][1][p0], q11 = prow[buf][1][p1];
            #pragma unroll
            for (int i = 0; i < 16; ++i) {
                bool pivotRow = (w == wp) && (i == i0 || i == i1);
                float f0 = __shfl(m[i], p0);
                float f1 = __shfl(m[i], p1);
                float nv = m[i] - f0 * s0 - f1 * s1;
                float wb0 = -(f0 * q00 + f1 * q10);
                float wb1 = -(f0 * q01 + f1 * q11);
                nv = (c == p0) ? wb0 : ((c == p1) ? wb1 : nv);
                if (!pivotRow) m[i] = nv;
            }
        }
    }

    #pragma unroll
    for (int i = 0; i < 16; ++i)
        Kinv[(w * 16 + i) * 64 + c] = m[i];
}

// ---------------------------------------------------------------------------
// Kernel B2: block i computes W[i][:] = Kinv[i][:] - (Kinv^2)[i][:],
// dotted with L[:,i].  (Proven in round 3.)
// ---------------------------------------------------------------------------
__global__ __launch_bounds__(64)
void trace_partial_kernel(const float* __restrict__ ws, float* __restrict__ partial) {
    const int i    = blockIdx.x;
    const int lane = threadIdx.x;
    const float* Lg   = ws + 4096;
    const float* Lt   = ws + 8192;
    const float* Lm   = ws + 12288;
    const float* Kinv = ws + 16384;

    float u = Kinv[i * 64 + lane];
    float acc = 0.0f;
    #pragma unroll 8
    for (int k = 0; k < 64; ++k)
        acc = fmaf(__shfl(u, k), Kinv[k * 64 + lane], acc);   // (Kinv^2)[i][lane]
    float wv = u - acc;

    float lc = Lg[lane * 64 + i] + Lt[lane * 64 + i] - 2.0f * Lm[lane * 64 + i];
    float local = wv * lc;
    #pragma unroll
    for (int off = 32; off > 0; off >>= 1)
        local += __shfl_down(local, off);
    if (lane == 0) partial[i] = local;
}

__global__ __launch_bounds__(64)
void final_sum_kernel(const float* __restrict__ partial, float* __restrict__ out) {
    float v = partial[threadIdx.x];
    #pragma unroll
    for (int off = 32; off > 0; off >>= 1)
        v += __shfl_down(v, off);
    if (threadIdx.x == 0) out[0] = v;
}

extern "C" void kernel_launch(void* const* d_in, const int* in_sizes, int n_in,
                              void* d_out, int out_size, void* d_ws, size_t ws_size,
                              hipStream_t stream) {
    const float* x = (const float*)d_in[0];
    const float* y = (const float*)d_in[1];
    const float* z = (const float*)d_in[2];
    float* out = (float*)d_out;
    float* ws  = (float*)d_ws;      // 20544 floats ≈ 80.3 KB used

    sigker_pde_kernel<<<5168, 64, 0, stream>>>(x, y, z, ws);
    gj_inverse_kernel<<<1, 256, 0, stream>>>(ws);
    trace_partial_kernel<<<64, 64, 0, stream>>>(ws, ws + 5 * 4096);
    final_sum_kernel<<<1, 64, 0, stream>>>(ws + 5 * 4096, out);
}

// Round 6
// 105.397 us; speedup vs baseline: 3.7431x; 1.2354x over previous
//
#include <hip/hip_runtime.h>
#include <hip/hip_fp16.h>
#include <math.h>

// ConditionalSigKerMMDDiscriminator — x,y,z: (64,33,8) fp32 -> scalar fp32.
//
//   K      = sigker(rbf(x,x))   [symmetric]
//   L_gen  = sigker(lin(y,y))   [symmetric]
//   L_true = sigker(lin(z,z))   [symmetric]
//   L_mix  = sigker(lin(y,z))   [full]
//   Kinv   = (K+I)^-1;  K*Kinv = I - Kinv  =>  W = Kinv - Kinv^2 (symmetric)
//   out    = sum_ij W[i][j]*(Lg+Lt-2Lm)[j][i]
//
// ws floats: [0]=K [4096]=Lg [8192]=Lt [12288]=Lm

#define SLEN 33

__device__ __forceinline__ float rl(float v, int lane) {
    return __int_as_float(__builtin_amdgcn_readlane(__float_as_int(v), lane));
}

// ---------------------------------------------------------------------------
// Kernel A: 2x2-block wavefront PDE (verified round 5, unchanged).
// One wave = 2 pairs (lane halves); lane p owns block-row p; 63 steps.
// fp16 inc: |inc|~1e-2, end-to-end absmax 0.031 << 0.149 budget.
// ---------------------------------------------------------------------------
__global__ __launch_bounds__(64, 5)
void sigker_pde_kernel(const float* __restrict__ x,
                       const float* __restrict__ y,
                       const float* __restrict__ z,
                       float* __restrict__ ws) {
    __shared__ float4 Xi4[2][66];
    __shared__ __half incH[2][1024];   // inc[row][col], row-major stride 32

    const int lane = threadIdx.x;
    const int h = lane >> 5;        // which pair in this wave
    const int p = lane & 31;        // block-row / build-column

    int b = blockIdx.x, g, loc;
    if (b < 1040)      { g = 0; loc = b; }
    else if (b < 2080) { g = 1; loc = b - 1040; }
    else if (b < 3120) { g = 2; loc = b - 2080; }
    else               { g = 3; loc = b - 3120; }

    int pair = 2 * loc + h, gi, gj;
    if (g == 3) {
        gi = pair >> 6; gj = pair & 63;
    } else {
        float ff = sqrtf(8.0f * (float)pair + 1.0f);
        gi = (int)((ff - 1.0f) * 0.5f);
        while ((gi + 1) * (gi + 2) / 2 <= pair) ++gi;
        while (gi * (gi + 1) / 2 > pair) --gi;
        gj = pair - gi * (gi + 1) / 2;
    }

    const float* Ap = (g == 0) ? x : ((g == 2) ? z : y);
    const float* Bp = (g == 0) ? x : ((g == 1) ? y : z);
    const float4* As = (const float4*)(Ap + gi * (SLEN * 8));
    const float4* Bs = (const float4*)(Bp + gj * (SLEN * 8));

    for (int k = p; k < 66; k += 32) Xi4[h][k] = As[k];
    float4 b0 = Bs[2*p],   b1 = Bs[2*p+1];
    float4 b2 = Bs[2*p+2], b3 = Bs[2*p+3];
    __syncthreads();

    if (g == 0) {
        // RBF: lane p slides down gram columns p and p+1; no gram tile.
        float nprev;
        {
            float4 a0 = Xi4[h][0], a1 = Xi4[h][1];
            float d0=a0.x-b0.x,d1=a0.y-b0.y,d2=a0.z-b0.z,d3=a0.w-b0.w;
            float d4=a1.x-b1.x,d5=a1.y-b1.y,d6=a1.z-b1.z,d7=a1.w-b1.w;
            float da = d0*d0+d1*d1+d2*d2+d3*d3+d4*d4+d5*d5+d6*d6+d7*d7;
            float e0=a0.x-b2.x,e1=a0.y-b2.y,e2=a0.z-b2.z,e3=a0.w-b2.w;
            float e4=a1.x-b3.x,e5=a1.y-b3.y,e6=a1.z-b3.z,e7=a1.w-b3.w;
            float db = e0*e0+e1*e1+e2*e2+e3*e3+e4*e4+e5*e5+e6*e6+e7*e7;
            nprev = __expf(-db) - __expf(-da);
        }
        for (int k = 1; k <= 32; ++k) {
            float4 a0 = Xi4[h][2*k], a1 = Xi4[h][2*k+1];
            float d0=a0.x-b0.x,d1=a0.y-b0.y,d2=a0.z-b0.z,d3=a0.w-b0.w;
            float d4=a1.x-b1.x,d5=a1.y-b1.y,d6=a1.z-b1.z,d7=a1.w-b1.w;
            float da = d0*d0+d1*d1+d2*d2+d3*d3+d4*d4+d5*d5+d6*d6+d7*d7;
            float e0=a0.x-b2.x,e1=a0.y-b2.y,e2=a0.z-b2.z,e3=a0.w-b2.w;
            float e4=a1.x-b3.x,e5=a1.y-b3.y,e6=a1.z-b3.z,e7=a1.w-b3.w;
            float db = e0*e0+e1*e1+e2*e2+e3*e3+e4*e4+e5*e5+e6*e6+e7*e7;
            float diffk = __expf(-db) - __expf(-da);
            incH[h][(k-1)*32 + p] = __float2half(0.25f * (diffk - nprev));
            nprev = diffk;
        }
    } else {
        // Linear: inc[k][p] = dXi[k]·dXj[p] / 4 (rank-1, no gram).
        float e0=b2.x-b0.x, e1=b2.y-b0.y, e2=b2.z-b0.z, e3=b2.w-b0.w;
        float e4=b3.x-b1.x, e5=b3.y-b1.y, e6=b3.z-b1.z, e7=b3.w-b1.w;
        float4 a0 = Xi4[h][0], a1 = Xi4[h][1];
        #pragma unroll 4
        for (int k = 0; k < 32; ++k) {
            float4 a2 = Xi4[h][2*k+2], a3 = Xi4[h][2*k+3];
            float acc = (a2.x-a0.x)*e0 + (a2.y-a0.y)*e1
                      + (a2.z-a0.z)*e2 + (a2.w-a0.w)*e3
                      + (a3.x-a1.x)*e4 + (a3.y-a1.y)*e5
                      + (a3.z-a1.z)*e6 + (a3.w-a1.w)*e7;
            incH[h][k*32 + p] = __float2half(0.25f * acc);
            a0 = a2; a1 = a3;
        }
    }
    __syncthreads();

    // 2x2-block anti-diagonal wavefront (verified rounds 3-5).
    float c01 = 1.0f, c10 = 1.0f, c11 = 1.0f, dcarry = 1.0f;
    const bool isrow0 = (p == 0);
    const __half* incrow = &incH[h][p * 32];
    #pragma unroll 4
    for (int m = 0; m < 63; ++m) {
        float nb10 = __shfl_up(c10, 1);
        float nb11 = __shfl_up(c11, 1);
        int t = m - p;
        float incv = __half2float(incrow[t & 31]);
        float n0 = isrow0 ? 1.0f : nb10;
        float n1 = isrow0 ? 1.0f : nb11;
        bool t0 = (t == 0);
        float w0 = t0 ? 1.0f : c01;
        float w1 = t0 ? 1.0f : c11;
        float d  = t0 ? 1.0f : dcarry;
        float i2 = incv * incv * (1.0f / 12.0f);
        float C1 = 1.0f + 0.5f * incv + i2;
        float C2 = 1.0f - i2;
        float v00 = (w0  + n0 ) * C1 - d   * C2;
        float v01 = (v00 + n1 ) * C1 - n0  * C2;
        float v10 = (v00 + w1 ) * C1 - w0  * C2;
        float v11 = (v10 + v01) * C1 - v00 * C2;
        c01 = v01; c10 = v10; c11 = v11;
        dcarry = n1;
    }

    if (p == 31) {
        float* dst = ws + g * 4096;
        dst[gi * 64 + gj] = c11;
        if (g != 3) dst[gj * 64 + gi] = c11;
    }
}

// ---------------------------------------------------------------------------
// Kernel B (fused): 2x2-block Gauss-Jordan inverse of (K+I) + trace, one
// block of 1024 threads (16 waves; 4 waves/SIMD for latency hiding).
// Thread (w=tid>>6, c=tid&63) owns rows w*4..w*4+3 in m[4] (static indices,
// no scratch). Fully-unrolled rounds => readlane (VALU, SGPR result) for all
// row-scalar fetches instead of DS-pipe shfls. One barrier per round via
// ping-pong prow. Then W = Kinv - Kinv^2 trace in the same block.
// ---------------------------------------------------------------------------
__global__ __launch_bounds__(1024, 1)
void gj_trace_kernel(const float* __restrict__ ws, float* __restrict__ out) {
    __shared__ float prow[2][2][64];
    __shared__ float Kls[64 * 65];
    __shared__ float red[16];

    const int tid = threadIdx.x;
    const int c = tid & 63, w = tid >> 6;   // w in 0..15, rows w*4+i
    const float* K  = ws;
    const float* Lg = ws + 4096;
    const float* Lt = ws + 8192;
    const float* Lm = ws + 12288;

    float m[4];
    #pragma unroll
    for (int i = 0; i < 4; ++i) {
        int r = w * 4 + i;
        m[i] = K[r * 64 + c] + ((r == c) ? 1.0f : 0.0f);   // K + I
    }

    #pragma unroll
    for (int rnd = 0; rnd < 32; ++rnd) {
        const int p0 = 2 * rnd, p1 = p0 + 1;     // compile-time constants
        const int wp = p0 >> 2;                  // wave owning rows p0,p1
        const int i0 = p0 & 3, i1 = i0 + 1;
        const int buf = rnd & 1;
        if (w == wp) {
            // 2x2 pivot block inverse (SPD principal block => det > 0)
            float a  = rl(m[i0], p0), bq = rl(m[i0], p1);
            float cq = rl(m[i1], p0), dq = rl(m[i1], p1);
            float dinv = 1.0f / (a * dq - bq * cq);
            float P00 =  dq * dinv, P01 = -bq * dinv;
            float P10 = -cq * dinv, P11 =  a  * dinv;
            float sp0 = P00 * m[i0] + P01 * m[i1];
            float sp1 = P10 * m[i0] + P11 * m[i1];
            sp0 = (c == p0) ? P00 : ((c == p1) ? P01 : sp0);
            sp1 = (c == p0) ? P10 : ((c == p1) ? P11 : sp1);
            m[i0] = sp0; m[i1] = sp1;
            prow[buf][0][c] = sp0;
            prow[buf][1][c] = sp1;
        }
        __syncthreads();
        float s0 = prow[buf][0][c],  s1 = prow[buf][1][c];
        float q00 = prow[buf][0][p0], q01 = prow[buf][0][p1];
        float q10 = prow[buf][1][p0], q11 = prow[buf][1][p1];
        #pragma unroll
        for (int i = 0; i < 4; ++i) {
            bool pivotRow = (w == wp) && (i == i0 || i == i1);
            float f0 = rl(m[i], p0);             // A[r][p0] (SGPR)
            float f1 = rl(m[i], p1);             // A[r][p1] (SGPR)
            float nv = m[i] - f0 * s0 - f1 * s1;
            float wb0 = -(f0 * q00 + f1 * q10);
            float wb1 = -(f0 * q01 + f1 * q11);
            nv = (c == p0) ? wb0 : ((c == p1) ? wb1 : nv);
            if (!pivotRow) m[i] = nv;
        }
        // next round writes prow[buf^1]; its barrier separates buf reuse
    }
    // m[i] = Kinv[w*4+i][c]

    #pragma unroll
    for (int i = 0; i < 4; ++i)
        Kls[(w * 4 + i) * 65 + c] = m[i];
    __syncthreads();

    // acc[i] = (Kinv^2)[w*4+i][c]; row scalar via dynamic-uniform readlane
    float acc[4] = {0.0f, 0.0f, 0.0f, 0.0f};
    #pragma unroll 4
    for (int k = 0; k < 64; ++k) {
        float rv = Kls[k * 65 + c];              // Kinv[k][c]
        #pragma unroll
        for (int i = 0; i < 4; ++i)
            acc[i] = fmaf(rl(m[i], k), rv, acc[i]);
    }

    // W = Kinv - Kinv^2 symmetric => tr(W L) = sum W[r][c]*Lc[r][c]
    float local = 0.0f;
    #pragma unroll
    for (int i = 0; i < 4; ++i) {
        int r = w * 4 + i;
        float lc = Lg[r * 64 + c] + Lt[r * 64 + c] - 2.0f * Lm[r * 64 + c];
        local += (m[i] - acc[i]) * lc;
    }
    #pragma unroll
    for (int off = 32; off > 0; off >>= 1)
        local += __shfl_down(local, off);
    if (c == 0) red[w] = local;
    __syncthreads();
    if (tid == 0) {
        float v = 0.0f;
        #pragma unroll
        for (int i = 0; i < 16; ++i) v += red[i];
        out[0] = v;
    }
}

extern "C" void kernel_launch(void* const* d_in, const int* in_sizes, int n_in,
                              void* d_out, int out_size, void* d_ws, size_t ws_size,
                              hipStream_t stream) {
    const float* x = (const float*)d_in[0];
    const float* y = (const float*)d_in[1];
    const float* z = (const float*)d_in[2];
    float* out = (float*)d_out;
    float* ws  = (float*)d_ws;      // 16384 floats = 64 KB used

    sigker_pde_kernel<<<5168, 64, 0, stream>>>(x, y, z, ws);
    gj_trace_kernel<<<1, 1024, 0, stream>>>(ws, out);
}